// Round 1
// baseline (235.131 us; speedup 1.0000x reference)
//
#include <hip/hip_runtime.h>

// R1 design:
//  k0: detect mask storage (int32 vs byte) -> flag in ws
//  k1: QKV projections (f32 in -> bf16 out). Q,K as [bh][nq][32]; V transposed [bh][32][nq]
//  k2: flash attention, 1 wave per 16 query rows, mfma_f32_16x16x32_bf16 for QK^T and PV,
//      online softmax, weights*mask fused, P transposed through padded LDS.
//  k3: output projection O_mid[b][nq][256] @ Wo^T + bo -> d_out (raw (b,nq,64) == (b,64,48,48))
// ws layout (bytes): Qbf 0..2359296, Kbf ..4718592, Vbf ..7077888, Omid(f32) ..11796480, flag int

typedef __attribute__((ext_vector_type(8))) short bf16x8;
typedef __attribute__((ext_vector_type(4))) float f32x4;

constexpr int B_  = 2;
constexpr int H_  = 8;
constexpr int NQ_ = 2304;
constexpr int DM_ = 64;
constexpr int DK_ = 32;
constexpr int NT_ = NQ_ / 32;   // 72 j-tiles of 32
constexpr float SCALE_ = 0.17677669529663687f;  // 1/sqrt(32)

static __device__ __forceinline__ unsigned short f2bf(float f) {
    unsigned int u = __builtin_bit_cast(unsigned int, f);
    u += 0x7fffu + ((u >> 16) & 1u);          // RNE; inputs here are finite
    return (unsigned short)(u >> 16);
}

// ---------------- k0: mask dtype detect ----------------
__global__ void detect_mask_k(const unsigned int* __restrict__ m, int* __restrict__ flag) {
    int t = threadIdx.x;                       // 64 threads, 1 wave
    unsigned int v = 0;
    for (int k = 0; k < 16; ++k) v |= m[t * 16 + k];   // first 4KB, safe in both modes
    unsigned long long b = __ballot(v > 1u);
    if (t == 0) *flag = (b != 0ull) ? 1 : 0;   // 1 => byte-packed bools
}

// ---------------- k1: QKV projections ----------------
__global__ __launch_bounds__(256) void proj_qkv_k(
    const float* __restrict__ qin, const float* __restrict__ kin, const float* __restrict__ vin,
    const float* __restrict__ Wq, const float* __restrict__ bq,
    const float* __restrict__ Wk, const float* __restrict__ bk,
    const float* __restrict__ Wv, const float* __restrict__ bv,
    unsigned short* __restrict__ Qbf, unsigned short* __restrict__ Kbf,
    unsigned short* __restrict__ Vbf)
{
    const int sel = blockIdx.y;
    const float* in  = sel == 0 ? qin : (sel == 1 ? kin : vin);
    const float* W   = sel == 0 ? Wq  : (sel == 1 ? Wk  : Wv);
    const float* bia = sel == 0 ? bq  : (sel == 1 ? bk  : bv);

    const int rt = blockIdx.x;                 // 0..(B*NQ/8-1)
    const int b  = rt / (NQ_ / 8);
    const int r0 = (rt % (NQ_ / 8)) * 8;

    __shared__ alignas(16) float ins[8][64];
    const int t = threadIdx.x;
    const float4* src = reinterpret_cast<const float4*>(in + ((size_t)b * NQ_ + r0) * DM_);
    if (t < 128) reinterpret_cast<float4*>(&ins[0][0])[t] = src[t];
    __syncthreads();

    float acc[8];
#pragma unroll
    for (int r = 0; r < 8; ++r) acc[r] = 0.f;
    const float* wrow = W + t * DM_;
    for (int m = 0; m < DM_; ++m) {
        float wv = wrow[m];
#pragma unroll
        for (int r = 0; r < 8; ++r) acc[r] += ins[r][m] * wv;
    }
    const float bb = bia[t];
    const int h = t >> 5, d = t & 31;
#pragma unroll
    for (int r = 0; r < 8; ++r) {
        unsigned short bvv = f2bf(acc[r] + bb);
        if (sel == 2) Vbf[(((size_t)b * H_ + h) * DK_ + d) * NQ_ + (r0 + r)] = bvv;
        else {
            unsigned short* out = (sel == 1) ? Kbf : Qbf;
            out[(((size_t)b * H_ + h) * NQ_ + (r0 + r)) * DK_ + d] = bvv;
        }
    }
}

// ---------------- k2: flash attention ----------------
__global__ __launch_bounds__(64) void attn_k(
    const unsigned short* __restrict__ Qbf,
    const unsigned short* __restrict__ Kbf,
    const unsigned short* __restrict__ Vbf,
    const float* __restrict__ attw,
    const unsigned char* __restrict__ maskb,
    const int* __restrict__ flagp,
    float* __restrict__ Omid)
{
    const int lane = threadIdx.x;
    const int l15 = lane & 15, hi = lane >> 4;
    const int bid = blockIdx.x;
    const int bh  = bid / (NQ_ / 16);
    const int it  = bid % (NQ_ / 16);
    const int i0  = it * 16;
    const int b   = bh / H_, h = bh % H_;
    const size_t mstride = (*flagp) ? 1 : 4;   // byte-index stride into mask storage

    __shared__ alignas(16) unsigned short Plds[16][40];   // padded: stride 40 bf16 = 80B

    const unsigned short* qbase = Qbf + (size_t)bh * NQ_ * DK_;
    const unsigned short* kbase = Kbf + (size_t)bh * NQ_ * DK_;
    const unsigned short* vbase = Vbf + (size_t)bh * DK_ * NQ_;
    const float* wbase = attw + (size_t)bh * NQ_ * NQ_;
    const size_t mbase = (size_t)bh * NQ_ * NQ_;

    // A-frag of Q: row=l15, k-slot (hi,e) -> d = 8*hi+e (consistent bijection everywhere)
    bf16x8 qa = *reinterpret_cast<const bf16x8*>(qbase + (size_t)(i0 + l15) * DK_ + 8 * hi);

    f32x4 oacc0 = {0.f, 0.f, 0.f, 0.f}, oacc1 = {0.f, 0.f, 0.f, 0.f};
    const f32x4 zero = {0.f, 0.f, 0.f, 0.f};
    float mrun[4], lrun[4];
#pragma unroll
    for (int r = 0; r < 4; ++r) { mrun[r] = -1e30f; lrun[r] = 0.f; }

    for (int t = 0; t < NT_; ++t) {
        const int j0 = t * 32;
        bf16x8 kb0 = *reinterpret_cast<const bf16x8*>(kbase + (size_t)(j0 + l15) * DK_ + 8 * hi);
        bf16x8 kb1 = *reinterpret_cast<const bf16x8*>(kbase + (size_t)(j0 + 16 + l15) * DK_ + 8 * hi);
        f32x4 s0 = __builtin_amdgcn_mfma_f32_16x16x32_bf16(qa, kb0, zero, 0, 0, 0);
        f32x4 s1 = __builtin_amdgcn_mfma_f32_16x16x32_bf16(qa, kb1, zero, 0, 0, 0);

        // apply scale * attention_weights, then mask -> -1e30
        float x0[4], x1[4];
#pragma unroll
        for (int r = 0; r < 4; ++r) {
            const int row = i0 + 4 * hi + r;
            const size_t rb = (size_t)row * NQ_;
            float w0 = wbase[rb + j0 + l15];
            float w1 = wbase[rb + j0 + 16 + l15];
            bool k0 = maskb[(mbase + rb + j0 + l15) * mstride] != 0;
            bool k1 = maskb[(mbase + rb + j0 + 16 + l15) * mstride] != 0;
            float xv0 = s0[r] * SCALE_ * w0;
            float xv1 = s1[r] * SCALE_ * w1;
            x0[r] = k0 ? -1e30f : xv0;
            x1[r] = k1 ? -1e30f : xv1;
        }

        // online softmax per row (rows live across the 16 lanes of each hi-group)
        float p0v[4], p1v[4];
#pragma unroll
        for (int r = 0; r < 4; ++r) {
            float tm = fmaxf(x0[r], x1[r]);
#pragma unroll
            for (int sh = 1; sh < 16; sh <<= 1) tm = fmaxf(tm, __shfl_xor(tm, sh, 64));
            float mnew = fmaxf(mrun[r], tm);
            float rf = expf(mrun[r] - mnew);           // ==1.0 when max unchanged
            float p0 = expf(x0[r] - mnew);
            float p1 = expf(x1[r] - mnew);
            float ts = p0 + p1;
#pragma unroll
            for (int sh = 1; sh < 16; sh <<= 1) ts += __shfl_xor(ts, sh, 64);
            lrun[r] = lrun[r] * rf + ts;
            mrun[r] = mnew;
            oacc0[r] *= rf;
            oacc1[r] *= rf;
            p0v[r] = p0; p1v[r] = p1;
        }

        // P -> LDS (bf16), transpose C-layout (row=4hi+r, col=l15) to A-layout (row=l15, k=8hi+e)
#pragma unroll
        for (int r = 0; r < 4; ++r) {
            Plds[4 * hi + r][l15]      = f2bf(p0v[r]);
            Plds[4 * hi + r][16 + l15] = f2bf(p1v[r]);
        }
        asm volatile("s_waitcnt lgkmcnt(0)" ::: "memory");  // same-wave cross-lane LDS fence
        bf16x8 pa  = *reinterpret_cast<const bf16x8*>(&Plds[l15][8 * hi]);
        bf16x8 vb0 = *reinterpret_cast<const bf16x8*>(vbase + (size_t)(l15) * NQ_ + j0 + 8 * hi);
        bf16x8 vb1 = *reinterpret_cast<const bf16x8*>(vbase + (size_t)(16 + l15) * NQ_ + j0 + 8 * hi);
        oacc0 = __builtin_amdgcn_mfma_f32_16x16x32_bf16(pa, vb0, oacc0, 0, 0, 0);
        oacc1 = __builtin_amdgcn_mfma_f32_16x16x32_bf16(pa, vb1, oacc1, 0, 0, 0);
    }

    float* ob = Omid + (size_t)b * NQ_ * 256 + h * DK_;
#pragma unroll
    for (int r = 0; r < 4; ++r) {
        float inv = 1.0f / lrun[r];
        const int row = i0 + 4 * hi + r;
        ob[(size_t)row * 256 + l15]      = oacc0[r] * inv;
        ob[(size_t)row * 256 + 16 + l15] = oacc1[r] * inv;
    }
}

// ---------------- k3: output projection ----------------
__global__ __launch_bounds__(256) void proj_out_k(
    const float* __restrict__ Omid, const float* __restrict__ Wo,
    const float* __restrict__ bo, float* __restrict__ out)
{
    const int rt = blockIdx.x;                 // 0..(B*NQ/16-1)
    const int b  = rt / (NQ_ / 16);
    const int r0 = (rt % (NQ_ / 16)) * 16;

    __shared__ alignas(16) float lds[16][256]; // 16KB
    const int t = threadIdx.x;
    const float4* src = reinterpret_cast<const float4*>(Omid + ((size_t)b * NQ_ + r0) * 256);
#pragma unroll
    for (int k = 0; k < 4; ++k) reinterpret_cast<float4*>(&lds[0][0])[t + k * 256] = src[t + k * 256];
    __syncthreads();

    const int m = t & 63, rg = t >> 6;
    float acc[4] = {0.f, 0.f, 0.f, 0.f};
    const float* wrow = Wo + m * 256;
    for (int c = 0; c < 256; ++c) {
        float wv = wrow[c];
#pragma unroll
        for (int rr = 0; rr < 4; ++rr) acc[rr] += lds[rg * 4 + rr][c] * wv;
    }
    const float bb = bo[m];
#pragma unroll
    for (int rr = 0; rr < 4; ++rr)
        out[((size_t)b * NQ_ + r0 + rg * 4 + rr) * 64 + m] = acc[rr] + bb;
}

extern "C" void kernel_launch(void* const* d_in, const int* in_sizes, int n_in,
                              void* d_out, int out_size, void* d_ws, size_t ws_size,
                              hipStream_t stream)
{
    (void)in_sizes; (void)n_in; (void)out_size; (void)ws_size;
    const float* qin  = (const float*)d_in[0];
    const float* kin  = (const float*)d_in[1];
    const float* vin  = (const float*)d_in[2];
    const float* attw = (const float*)d_in[3];
    const void*  mask = d_in[4];
    const float* Wq = (const float*)d_in[5];
    const float* bq = (const float*)d_in[6];
    const float* Wk = (const float*)d_in[7];
    const float* bk = (const float*)d_in[8];
    const float* Wv = (const float*)d_in[9];
    const float* bv = (const float*)d_in[10];
    const float* Wo = (const float*)d_in[11];
    const float* bo = (const float*)d_in[12];

    char* ws = (char*)d_ws;
    unsigned short* Qbf = (unsigned short*)(ws);
    unsigned short* Kbf = (unsigned short*)(ws + 2359296);
    unsigned short* Vbf = (unsigned short*)(ws + 4718592);
    float*          Omid = (float*)(ws + 7077888);
    int*            flag = (int*)(ws + 11796480);

    detect_mask_k<<<1, 64, 0, stream>>>((const unsigned int*)mask, flag);
    proj_qkv_k<<<dim3(B_ * NQ_ / 8, 3), 256, 0, stream>>>(
        qin, kin, vin, Wq, bq, Wk, bk, Wv, bv, Qbf, Kbf, Vbf);
    attn_k<<<B_ * H_ * (NQ_ / 16), 64, 0, stream>>>(
        Qbf, Kbf, Vbf, attw, (const unsigned char*)mask, flag, Omid);
    proj_out_k<<<B_ * NQ_ / 16, 256, 0, stream>>>(Omid, Wo, bo, (float*)d_out);
}